// Round 7
// baseline (95.320 us; speedup 1.0000x reference)
//
#include <hip/hip_runtime.h>
#include <cstdint>
#include <cstddef>

#define TABLE_SIZE 524288   // 2^19
#define CROP 256
#define TILE 16             // 16x16 px per block, 1 px/thread

// grid resolutions: int(round(16 * 1.5^l)), Python banker's rounding (121.5->122)
constexpr int LN[16] = {16, 24, 36, 54, 81, 122, 182, 273, 410, 615, 923, 1384, 2076, 3114, 4671, 7006};
// per-level staged-rectangle width NX = floor(15*N/4096)+4 (bound verified in R4)
constexpr int NXA[16] = {4,4,4,4,4,4,4,4,5,6,7,9,11,15,21,29};
#define SEED(l) ((uint32_t)(15485907386658061715ULL ^ ((uint64_t)(l) * 11400714819323198485ULL)))
constexpr uint32_t SEEDC[16] = {SEED(0),SEED(1),SEED(2),SEED(3),SEED(4),SEED(5),SEED(6),SEED(7),
                                SEED(8),SEED(9),SEED(10),SEED(11),SEED(12),SEED(13),SEED(14),SEED(15)};

// Level-phased hash-grid encoder with double-buffered async staging:
// iter l = { issue gathers for l+1 -> regs | bilinear level l from LDS + NT store |
//            ds_write regs -> other buffer | barrier }.
// 256-thr blocks, 13.6 KB LDS -> 8 blocks/CU: 8 independent barrier domains/CU
// hide each block's gather tail (R6 lesson: small blocks + many co-resident
// blocks beat wide blocks). Crop->XCD pinning keeps each XCD's live table set
// ~= one level (R4 lesson: all-levels-at-once thrashes the 4 MiB L2).
__global__ __launch_bounds__(256)
void HashTableEncoder2D_59339268161685_kernel(const float* __restrict__ tables,
                                              const int* __restrict__ x0,
                                              const int* __restrict__ y0,
                                              float* __restrict__ out)
{
    __shared__ float2 buf[2][848];   // 848 >= max NX^2 = 841; 13,568 B total

    // blockIdx = xcd + 8*s: XCD k owns crops {2k, 2k+1}
    const int xcd  = blockIdx.x & 7;
    const int s    = blockIdx.x >> 3;        // [0,512)
    const int b    = 2 * xcd + (s >> 8);     // crop id
    const int tile = s & 255;                // 16x16 tiles of 16x16 px
    const int tx = (tile & 15) * TILE;
    const int ty = (tile >> 4) * TILE;
    const int tid = threadIdx.x;

    // tile-origin pixel center; exact in f32 (k+0.5, k < 2^22)
    const float bx = (float)(x0[b] + tx) + 0.5f;
    const float by = (float)(y0[b] + ty) + 0.5f;

    const int j = tid & 15;
    const int i = tid >> 4;
    const float px = bx + (float)j;   // exact; equals reference pxf
    const float py = by + (float)i;

    float* o0 = out + (size_t)b * (size_t)(32 * CROP * CROP)
                    + (ty + i) * CROP + (tx + j);

    // ---- prologue: stage level 0 (16 corners) into buf[0] ----
    {
        const float sc = (float)LN[0] * (1.0f / 4096.0f);
        const int ixlo = (int)floorf(bx * sc);
        const int iylo = (int)floorf(by * sc);
        if (tid < 16) {
            const int row = tid >> 2, col = tid & 3;
            const uint32_t h = ((uint32_t)(ixlo + col) * 2654435761u)
                             ^ ((uint32_t)(iylo + row) * 805459861u) ^ SEEDC[0];
            buf[0][tid] = ((const float2*)tables)[h & (TABLE_SIZE - 1)];
        }
    }
    __syncthreads();

    #pragma unroll
    for (int l = 0; l < 16; ++l) {
        float2 r[4];   // staged corners for level l+1 (statically indexed)

        // ---- 1) issue gathers for level l+1 (latency hides under step 2) ----
        if (l < 15) {
            const int lp  = l + 1;
            const int NX  = NXA[lp];          // compile-time after unroll
            const int CNT = NX * NX;
            const float sc = (float)LN[lp] * (1.0f / 4096.0f);
            const int ixlo = (int)floorf(bx * sc);
            const int iylo = (int)floorf(by * sc);
            const float2* __restrict__ T =
                (const float2*)tables + (size_t)lp * TABLE_SIZE;
            #pragma unroll
            for (int k = 0; k < 4; ++k) {
                if (k * 256 < CNT) {
                    const int c = tid + (k << 8);
                    if (c < CNT) {
                        const int row = c / NX;       // const divisor -> magic mul
                        const int col = c - row * NX;
                        const uint32_t h = ((uint32_t)(ixlo + col) * 2654435761u)
                                         ^ ((uint32_t)(iylo + row) * 805459861u) ^ SEEDC[lp];
                        r[k] = T[h & (TABLE_SIZE - 1)];
                    }
                }
            }
        }

        // ---- 2) bilinear for level l from buf[l&1] ----
        {
            const int NX = NXA[l];
            const float sc = (float)LN[l] * (1.0f / 4096.0f);
            const int ixlo = (int)floorf(bx * sc);   // identical ops to staging
            const int iylo = (int)floorf(by * sc);

            const float gx = px * sc;
            const float gy = py * sc;
            const float fxf = floorf(gx);
            const float fyf = floorf(gy);
            const float fx = gx - fxf;
            const float fy = gy - fyf;
            const int base = ((int)fyf - iylo) * NX + ((int)fxf - ixlo);

            const float2* __restrict__ B = buf[l & 1];
            const float2 f00 = B[base];
            const float2 f10 = B[base + 1];
            const float2 f01 = B[base + NX];
            const float2 f11 = B[base + NX + 1];

            const float w00 = (1.0f - fx) * (1.0f - fy);
            const float w10 = fx * (1.0f - fy);
            const float w01 = (1.0f - fx) * fy;
            const float w11 = fx * fy;

            const float e0 = w00 * f00.x + w10 * f10.x + w01 * f01.x + w11 * f11.x;
            const float e1 = w00 * f00.y + w10 * f10.y + w01 * f01.y + w11 * f11.y;

            __builtin_nontemporal_store(e0, o0 + (size_t)(2 * l)     * (CROP * CROP));
            __builtin_nontemporal_store(e1, o0 + (size_t)(2 * l + 1) * (CROP * CROP));
        }

        // ---- 3) write staged regs into the other buffer, 4) barrier ----
        if (l < 15) {
            const int lp  = l + 1;
            const int NX  = NXA[lp];
            const int CNT = NX * NX;
            float2* __restrict__ B = buf[lp & 1];
            #pragma unroll
            for (int k = 0; k < 4; ++k) {
                if (k * 256 < CNT) {
                    const int c = tid + (k << 8);
                    if (c < CNT) B[c] = r[k];
                }
            }
        }
        __syncthreads();
    }
}

extern "C" void kernel_launch(void* const* d_in, const int* in_sizes, int n_in,
                              void* d_out, int out_size, void* d_ws, size_t ws_size,
                              hipStream_t stream)
{
    const float* tables = (const float*)d_in[0];
    const int*   x0     = (const int*)d_in[1];
    const int*   y0     = (const int*)d_in[2];
    float* out = (float*)d_out;

    // 16 crops x 256 tiles (16x16 px) = 4096 blocks x 256 threads
    HashTableEncoder2D_59339268161685_kernel<<<4096, 256, 0, stream>>>(tables, x0, y0, out);
}

// Round 8
// 69.652 us; speedup vs baseline: 1.3685x; 1.3685x over previous
//
#include <hip/hip_runtime.h>
#include <cstdint>
#include <cstddef>

#define TABLE_SIZE 524288   // 2^19
#define CROP 256
#define TILE 32             // 32x32 px per block (settled: best FETCH/WRITE tradeoff)
#define NXS 40              // staged LDS stride; max staged level l14: nx <= 39

// staged levels 0..14 (level 15 is direct-gathered)
__device__ __constant__ int c_levelN[15] = {
    16, 24, 36, 54, 81, 122, 182, 273, 410, 615, 923, 1384, 2076, 3114, 4671
};
#define SEED(l) ((uint32_t)(15485907386658061715ULL ^ ((uint64_t)(l) * 11400714819323198485ULL)))
__device__ __constant__ uint32_t c_seed[15] = {
    SEED(0),SEED(1),SEED(2),SEED(3),SEED(4),SEED(5),SEED(6),SEED(7),
    SEED(8),SEED(9),SEED(10),SEED(11),SEED(12),SEED(13),SEED(14)
};

// R3 structure (level-phased LDS corner dedup, 32x32 tiles, 256 thr, crop->XCD
// pinning) + two upgrades:
//  (1) level 15 skips LDS (dedup ratio only 0.77): its 16 float2 gathers are
//      issued at kernel START and consumed LAST -> latency hidden under the
//      15 staged levels; kills the largest staging phase + 2 barriers.
//  (2) LDS stride 57 -> 40 (l14 max): 26 KB -> 12.8 KB, 6 -> 8 blocks/CU.
__global__ __launch_bounds__(256, 8)
void HashTableEncoder2D_59339268161685_kernel(const float* __restrict__ tables,
                                              const int* __restrict__ x0,
                                              const int* __restrict__ y0,
                                              float* __restrict__ out)
{
    __shared__ float2 lds[NXS * NXS];   // 12,800 B

    // blockIdx = xcd + 8*s: XCD k owns crops {2k, 2k+1}
    const int xcd  = blockIdx.x & 7;
    const int s    = blockIdx.x >> 3;        // [0,128)
    const int b    = 2 * xcd + (s >> 6);     // crop id
    const int tile = s & 63;                 // 8x8 tiles of 32x32 px
    const int tx = (tile & 7) * TILE;
    const int ty = (tile >> 3) * TILE;
    const int tid = threadIdx.x;

    // tile-origin pixel center; exact in f32
    const float bx = (float)(x0[b] + tx) + 0.5f;
    const float by = (float)(y0[b] + ty) + 0.5f;

    // thread's 4 px: fixed column j, rows i0+8k (k=0..3)
    const int j  = tid & 31;
    const int i0 = tid >> 5;
    const float px = bx + (float)j;   // exact; equals reference pxf

    float* ocol = out + (size_t)b * (size_t)(32 * CROP * CROP)
                      + (size_t)ty * CROP + (tx + j);

    // ---- issue level-15 gathers now; consumed after all staged levels ----
    float2 g15[16];
    {
        const float sc = 7006.0f * (1.0f / 4096.0f);   // exact dyadic
        const uint32_t seed = SEED(15);
        const float gx = px * sc;
        const int ix0 = (int)floorf(gx);
        const uint32_t hx0 = (uint32_t)ix0 * 2654435761u;
        const uint32_t hx1 = (uint32_t)(ix0 + 1) * 2654435761u;
        const float2* __restrict__ T = (const float2*)tables + (size_t)15 * TABLE_SIZE;
        #pragma unroll
        for (int k = 0; k < 4; ++k) {
            const float gy = (by + (float)(i0 + 8 * k)) * sc;
            const int iy0 = (int)floorf(gy);
            const uint32_t hy0 = ((uint32_t)iy0 * 805459861u) ^ seed;
            const uint32_t hy1 = ((uint32_t)(iy0 + 1) * 805459861u) ^ seed;
            g15[4 * k + 0] = T[(hx0 ^ hy0) & (TABLE_SIZE - 1)];
            g15[4 * k + 1] = T[(hx1 ^ hy0) & (TABLE_SIZE - 1)];
            g15[4 * k + 2] = T[(hx0 ^ hy1) & (TABLE_SIZE - 1)];
            g15[4 * k + 3] = T[(hx1 ^ hy1) & (TABLE_SIZE - 1)];
        }
    }

    // ---- staged levels 0..14 (verified R3 math, stride 40) ----
    for (int l = 0; l < 15; ++l) {
        const float scale = (float)c_levelN[l] * (1.0f / 4096.0f); // exact dyadic
        const uint32_t seed = c_seed[l];

        const int ixlo = (int)floorf(bx * scale);
        const int iylo = (int)floorf(by * scale);
        const int nx = ((int)floorf((bx + 31.0f) * scale) + 1) - ixlo + 1; // <= 39
        const int ny = ((int)floorf((by + 31.0f) * scale) + 1) - iylo + 1;

        __syncthreads();   // previous level's LDS readers done

        const float2* __restrict__ T =
            (const float2*)tables + (size_t)l * TABLE_SIZE;
        for (int c = tid; c < NXS * ny; c += 256) {
            const int row = c / NXS;              // const divisor -> magic mul
            const int col = c - row * NXS;
            if (col < nx) {
                const uint32_t h = ((uint32_t)(ixlo + col) * 2654435761u)
                                 ^ ((uint32_t)(iylo + row) * 805459861u) ^ seed;
                lds[c] = T[h & (TABLE_SIZE - 1)];
            }
        }
        __syncthreads();

        const float gx = px * scale;
        const float fxf = floorf(gx);
        const float fx = gx - fxf;
        const int cb = (int)fxf - ixlo;

        #pragma unroll
        for (int k = 0; k < 4; ++k) {
            const int i = i0 + 8 * k;
            const float gy = (by + (float)i) * scale;
            const float fyf = floorf(gy);
            const float fy = gy - fyf;
            const int base = ((int)fyf - iylo) * NXS + cb;

            const float2 f00 = lds[base];
            const float2 f10 = lds[base + 1];
            const float2 f01 = lds[base + NXS];
            const float2 f11 = lds[base + NXS + 1];

            const float w00 = (1.0f - fx) * (1.0f - fy);
            const float w10 = fx * (1.0f - fy);
            const float w01 = (1.0f - fx) * fy;
            const float w11 = fx * fy;

            const float e0 = w00 * f00.x + w10 * f10.x + w01 * f01.x + w11 * f11.x;
            const float e1 = w00 * f00.y + w10 * f10.y + w01 * f01.y + w11 * f11.y;

            float* o = ocol + i * CROP;
            __builtin_nontemporal_store(e0, o + (size_t)(2 * l)     * (CROP * CROP));
            __builtin_nontemporal_store(e1, o + (size_t)(2 * l + 1) * (CROP * CROP));
        }
    }

    // ---- level 15 from the early-issued registers ----
    {
        const float sc = 7006.0f * (1.0f / 4096.0f);
        const float gx = px * sc;
        const float fxf = floorf(gx);
        const float fx = gx - fxf;

        #pragma unroll
        for (int k = 0; k < 4; ++k) {
            const int i = i0 + 8 * k;
            const float gy = (by + (float)i) * sc;
            const float fyf = floorf(gy);
            const float fy = gy - fyf;

            const float w00 = (1.0f - fx) * (1.0f - fy);
            const float w10 = fx * (1.0f - fy);
            const float w01 = (1.0f - fx) * fy;
            const float w11 = fx * fy;

            const float2 f00 = g15[4 * k + 0];
            const float2 f10 = g15[4 * k + 1];
            const float2 f01 = g15[4 * k + 2];
            const float2 f11 = g15[4 * k + 3];

            const float e0 = w00 * f00.x + w10 * f10.x + w01 * f01.x + w11 * f11.x;
            const float e1 = w00 * f00.y + w10 * f10.y + w01 * f01.y + w11 * f11.y;

            float* o = ocol + i * CROP;
            __builtin_nontemporal_store(e0, o + (size_t)30 * (CROP * CROP));
            __builtin_nontemporal_store(e1, o + (size_t)31 * (CROP * CROP));
        }
    }
}

extern "C" void kernel_launch(void* const* d_in, const int* in_sizes, int n_in,
                              void* d_out, int out_size, void* d_ws, size_t ws_size,
                              hipStream_t stream)
{
    const float* tables = (const float*)d_in[0];
    const int*   x0     = (const int*)d_in[1];
    const int*   y0     = (const int*)d_in[2];
    float* out = (float*)d_out;

    // 16 crops x 64 tiles = 1024 blocks x 256 threads
    HashTableEncoder2D_59339268161685_kernel<<<1024, 256, 0, stream>>>(tables, x0, y0, out);
}